// Round 1
// baseline (552.451 us; speedup 1.0000x reference)
//
#include <hip/hip_runtime.h>
#include <math.h>

#define BB 4
#define NN 1024
#define CC 384
#define KK 10
#define NKK (NN*KK)

__device__ __forceinline__ float wave_sum(float v) {
  #pragma unroll
  for (int off = 32; off > 0; off >>= 1) v += __shfl_xor(v, off, 64);
  return v;
}

// ---------------- prep: Wdiff = Wk_bot - Wk_top ; c1 = bv@W1_top + b1 ----------------
__global__ void wdiff_kernel(const float* __restrict__ Wk, float* __restrict__ Wdiff) {
  int i = blockIdx.x * blockDim.x + threadIdx.x;
  if (i < CC * CC) Wdiff[i] = Wk[CC * CC + i] - Wk[i];
}

__global__ void c1_kernel(const float* __restrict__ W1, const float* __restrict__ b1,
                          const float* __restrict__ bv, float* __restrict__ c1) {
  int j = blockIdx.x * blockDim.x + threadIdx.x;
  if (j < CC) {
    float s = b1[j];
    for (int i = 0; i < CC; ++i) s += bv[i] * W1[i * CC + j];
    c1[j] = s;
  }
}

// ---------------- generic f32 GEMM: C[M,Ncol] = A[M,Kd]@B[Kd,Ncol] (+bias) ----------
// 64x64 tile, BK=16, 256 threads, 4x4 per thread. All dims multiples of 64/16 here.
__global__ __launch_bounds__(256) void gemm_kernel(
    const float* __restrict__ A, const float* __restrict__ Bm,
    float* __restrict__ Cm, const float* __restrict__ bias,
    int M, int Ncol, int Kd) {
  __shared__ float As[16][64];
  __shared__ float Bs[16][64];
  int tid = threadIdx.x;
  int tx = tid & 15, ty = tid >> 4;
  int row0 = blockIdx.y * 64, col0 = blockIdx.x * 64;
  int arow = tid >> 2, ak4 = (tid & 3) << 2;
  int brow = tid >> 4, bc4 = (tid & 15) << 2;
  float acc[4][4] = {};
  for (int kt = 0; kt < Kd; kt += 16) {
    float4 av = *reinterpret_cast<const float4*>(A + (size_t)(row0 + arow) * Kd + kt + ak4);
    float4 bv4 = *reinterpret_cast<const float4*>(Bm + (size_t)(kt + brow) * Ncol + col0 + bc4);
    As[ak4 + 0][arow] = av.x;
    As[ak4 + 1][arow] = av.y;
    As[ak4 + 2][arow] = av.z;
    As[ak4 + 3][arow] = av.w;
    *reinterpret_cast<float4*>(&Bs[brow][bc4]) = bv4;
    __syncthreads();
    #pragma unroll
    for (int kk = 0; kk < 16; ++kk) {
      float4 a = *reinterpret_cast<const float4*>(&As[kk][ty << 2]);
      float4 bb = *reinterpret_cast<const float4*>(&Bs[kk][tx << 2]);
      float av_[4] = {a.x, a.y, a.z, a.w};
      float bv_[4] = {bb.x, bb.y, bb.z, bb.w};
      #pragma unroll
      for (int i = 0; i < 4; ++i)
        #pragma unroll
        for (int j = 0; j < 4; ++j)
          acc[i][j] += av_[i] * bv_[j];
    }
    __syncthreads();
  }
  #pragma unroll
  for (int i = 0; i < 4; ++i) {
    int row = row0 + (ty << 2) + i;
    int col = col0 + (tx << 2);
    float4 r;
    r.x = acc[i][0]; r.y = acc[i][1]; r.z = acc[i][2]; r.w = acc[i][3];
    if (bias) { r.x += bias[col]; r.y += bias[col + 1]; r.z += bias[col + 2]; r.w += bias[col + 3]; }
    *reinterpret_cast<float4*>(Cm + (size_t)row * Ncol + col) = r;
  }
}

// ---------------- KNN: top-10 smallest sqdist among all 1024 points (per batch) ------
__global__ __launch_bounds__(64) void knn_kernel(const float* __restrict__ q_pos,
                                                 int* __restrict__ idx_out) {
  __shared__ float sx[NN], sy[NN], sz[NN];
  int b = blockIdx.y;
  int t = threadIdx.x;
  const float* qp = q_pos + (size_t)b * NN * 3;
  for (int i = t; i < NN; i += 64) {
    sx[i] = qp[i * 3 + 0]; sy[i] = qp[i * 3 + 1]; sz[i] = qp[i * 3 + 2];
  }
  __syncthreads();
  int n = blockIdx.x * 64 + t;
  double px = (double)sx[n], py = (double)sy[n], pz = (double)sz[n];
  double sp = px * px + py * py + pz * pz;
  double bd[KK]; int bi[KK];
  #pragma unroll
  for (int s = 0; s < KK; ++s) { bd[s] = 1e300; bi[s] = -1; }
  for (int m = 0; m < NN; ++m) {
    double mx = (double)sx[m], my = (double)sy[m], mz = (double)sz[m];
    double d = sp + (mx * mx + my * my + mz * mz) - 2.0 * (px * mx + py * my + pz * mz);
    if (d < 0.0) d = 0.0;
    if (d < bd[KK - 1]) {   // strict < keeps earlier (lower-index) ties: stable like lax.top_k
      bd[KK - 1] = d; bi[KK - 1] = m;
      #pragma unroll
      for (int s = KK - 1; s >= 1; --s) {
        if (bd[s] < bd[s - 1]) {
          double td = bd[s]; bd[s] = bd[s - 1]; bd[s - 1] = td;
          int ti = bi[s]; bi[s] = bi[s - 1]; bi[s - 1] = ti;
        }
      }
    }
  }
  int* op = idx_out + ((size_t)b * NN + n) * KK;
  #pragma unroll
  for (int s = 0; s < KK; ++s) op[s] = bi[s];
}

// -------- fused MLP per (b,n,k): h=U[idx]+V+c1 -> LN -> gelu -> tanh(h@W2) -> shift_pos
__global__ __launch_bounds__(64) void mlp_kernel(
    const float* __restrict__ U, const float* __restrict__ V, const float* __restrict__ c1,
    const float* __restrict__ lng, const float* __restrict__ lnb, const float* __restrict__ W2,
    const int* __restrict__ idxk, const float* __restrict__ q_pos,
    float* __restrict__ shp) {
  int gid = blockIdx.x;                 // (b*NN+n)*KK + k
  int k = gid % KK;
  int bn = gid / KK;
  int b = bn / NN;
  int lane = threadIdx.x;
  const int* nb = idxk + (size_t)bn * KK;
  int me = nb[k];
  __shared__ float s_scale[3], s_lv[3];
  if (lane < 3) {
    float mx = -1e30f, mn = 1e30f;
    #pragma unroll
    for (int kk2 = 0; kk2 < KK; ++kk2) {
      float v = q_pos[((size_t)b * NN + nb[kk2]) * 3 + lane];
      mx = fmaxf(mx, v); mn = fminf(mn, v);
    }
    s_scale[lane] = (mx - mn) * 0.5f;
    s_lv[lane] = q_pos[((size_t)b * NN + me) * 3 + lane];
  }
  const float* Urow = U + ((size_t)b * NN + me) * CC;
  const float* Vrow = V + (size_t)bn * CC;
  float h[6];
  float ls = 0.f;
  #pragma unroll
  for (int i = 0; i < 6; ++i) {
    int c = lane + i * 64;
    h[i] = Urow[c] + Vrow[c] + c1[c];
    ls += h[i];
  }
  ls = wave_sum(ls);
  float mu = ls * (1.0f / CC);
  float lv = 0.f;
  #pragma unroll
  for (int i = 0; i < 6; ++i) { float d = h[i] - mu; lv += d * d; }
  lv = wave_sum(lv);
  float rstd = 1.0f / sqrtf(lv * (1.0f / CC) + 1e-5f);
  float o0 = 0.f, o1 = 0.f, o2 = 0.f;
  #pragma unroll
  for (int i = 0; i < 6; ++i) {
    int c = lane + i * 64;
    float x = (h[i] - mu) * rstd * lng[c] + lnb[c];
    float g = 0.5f * x * (1.0f + erff(x * 0.70710678118654752440f));  // exact gelu
    o0 += g * W2[c * 3 + 0];
    o1 += g * W2[c * 3 + 1];
    o2 += g * W2[c * 3 + 2];
  }
  o0 = wave_sum(o0); o1 = wave_sum(o1); o2 = wave_sum(o2);
  __syncthreads();
  if (lane == 0) {
    float* sp = shp + ((size_t)bn * KK + k) * 3;
    sp[0] = s_lv[0] + tanhf(o0) * s_scale[0];
    sp[1] = s_lv[1] + tanhf(o1) * s_scale[1];
    sp[2] = s_lv[2] + tanhf(o2) * s_scale[2];
  }
}

// ---------------- three_nn: top-3 smallest sqdist of shift_pos vs q_pos + weights ----
__global__ __launch_bounds__(64) void three_nn_kernel(
    const float* __restrict__ q_pos, const float* __restrict__ shp,
    float* __restrict__ w3, int* __restrict__ i3) {
  __shared__ float sx[NN], sy[NN], sz[NN];
  int b = blockIdx.y;
  int t = threadIdx.x;
  const float* qp = q_pos + (size_t)b * NN * 3;
  for (int i = t; i < NN; i += 64) {
    sx[i] = qp[i * 3 + 0]; sy[i] = qp[i * 3 + 1]; sz[i] = qp[i * 3 + 2];
  }
  __syncthreads();
  int p = blockIdx.x * 64 + t;
  const float* spnt = shp + ((size_t)b * NKK + p) * 3;
  double px = (double)spnt[0], py = (double)spnt[1], pz = (double)spnt[2];
  double sp = px * px + py * py + pz * pz;
  double d0 = 1e300, d1 = 1e300, d2 = 1e300;
  int i0 = -1, i1 = -1, i2 = -1;
  for (int m = 0; m < NN; ++m) {
    double mx = (double)sx[m], my = (double)sy[m], mz = (double)sz[m];
    double d = sp + (mx * mx + my * my + mz * mz) - 2.0 * (px * mx + py * my + pz * mz);
    if (d < 0.0) d = 0.0;
    if (d < d2) {
      if (d < d1) {
        d2 = d1; i2 = i1;
        if (d < d0) { d1 = d0; i1 = i0; d0 = d; i0 = m; }
        else { d1 = d; i1 = m; }
      } else { d2 = d; i2 = m; }
    }
  }
  double w0 = 1.0 / (d0 + 1e-8), w1 = 1.0 / (d1 + 1e-8), w2 = 1.0 / (d2 + 1e-8);
  double s = w0 + w1 + w2;
  float* wp = w3 + ((size_t)b * NKK + p) * 3;
  int* ip = i3 + ((size_t)b * NKK + p) * 3;
  wp[0] = (float)(w0 / s); wp[1] = (float)(w1 / s); wp[2] = (float)(w2 / s);
  ip[0] = i0; ip[1] = i1; ip[2] = i2;
}

// ------- final: out[b,n,j] = max_k lrelu( sum_t w*P[idx3_t,j] + Bse[b,n,j] ) ---------
__global__ __launch_bounds__(384) void final_kernel(
    const float* __restrict__ P, const float* __restrict__ Bse,
    const float* __restrict__ w3, const int* __restrict__ i3,
    float* __restrict__ out) {
  int b = blockIdx.y, n = blockIdx.x;
  int j = threadIdx.x;
  __shared__ float sw[KK * 3];
  __shared__ int si[KK * 3];
  if (j < KK * 3) {
    size_t base = ((size_t)b * NKK + (size_t)n * KK) * 3 + j;
    sw[j] = w3[base];
    si[j] = i3[base];
  }
  __syncthreads();
  float base = Bse[((size_t)b * NN + n) * CC + j];
  const float* Pb = P + (size_t)b * NN * CC;
  float best = -1e30f;
  #pragma unroll
  for (int k = 0; k < KK; ++k) {
    float acc = base;
    #pragma unroll
    for (int tt = 0; tt < 3; ++tt)
      acc += sw[k * 3 + tt] * Pb[(size_t)si[k * 3 + tt] * CC + j];
    acc = acc >= 0.f ? acc : 0.2f * acc;
    best = fmaxf(best, acc);
  }
  out[((size_t)b * NN + n) * CC + j] = best;
}

extern "C" void kernel_launch(void* const* d_in, const int* in_sizes, int n_in,
                              void* d_out, int out_size, void* d_ws, size_t ws_size,
                              hipStream_t stream) {
  (void)in_sizes; (void)n_in; (void)out_size; (void)ws_size;
  const float* q    = (const float*)d_in[0];
  const float* qpos = (const float*)d_in[1];
  const float* Wv   = (const float*)d_in[2];
  const float* bv   = (const float*)d_in[3];
  const float* W1   = (const float*)d_in[4];
  const float* b1   = (const float*)d_in[5];
  const float* lng  = (const float*)d_in[6];
  const float* lnb  = (const float*)d_in[7];
  const float* W2   = (const float*)d_in[8];
  const float* Wk   = (const float*)d_in[9];
  const float* bk   = (const float*)d_in[10];
  float* out = (float*)d_out;

  float* ws = (float*)d_ws;
  float* M1    = ws; ws += CC * CC;
  float* Wdiff = ws; ws += CC * CC;
  float* c1    = ws; ws += CC;
  float* U     = ws; ws += BB * NN * CC;
  float* V     = ws; ws += BB * NN * CC;
  float* P     = ws; ws += BB * NN * CC;
  float* Bse   = ws; ws += BB * NN * CC;
  float* shp   = ws; ws += BB * NKK * 3;
  float* w3    = ws; ws += BB * NKK * 3;
  int* idxk = (int*)ws;
  int* i3   = idxk + BB * NN * KK;

  // prep
  wdiff_kernel<<<dim3((CC * CC + 255) / 256), dim3(256), 0, stream>>>(Wk, Wdiff);
  c1_kernel<<<dim3(2), dim3(192), 0, stream>>>(W1, b1, bv, c1);

  // M1 = Wv @ W1_top
  gemm_kernel<<<dim3(CC / 64, CC / 64), dim3(256), 0, stream>>>(Wv, W1, M1, nullptr, CC, CC, CC);
  // U = q @ M1 ; V = q @ W1_bot ; P = q @ Wk_top ; Bse = q @ (Wk_bot-Wk_top) + bk
  gemm_kernel<<<dim3(CC / 64, BB * NN / 64), dim3(256), 0, stream>>>(q, M1, U, nullptr, BB * NN, CC, CC);
  gemm_kernel<<<dim3(CC / 64, BB * NN / 64), dim3(256), 0, stream>>>(q, W1 + CC * CC, V, nullptr, BB * NN, CC, CC);
  gemm_kernel<<<dim3(CC / 64, BB * NN / 64), dim3(256), 0, stream>>>(q, Wk, P, nullptr, BB * NN, CC, CC);
  gemm_kernel<<<dim3(CC / 64, BB * NN / 64), dim3(256), 0, stream>>>(q, Wdiff, Bse, bk, BB * NN, CC, CC);

  // topology + pointwise
  knn_kernel<<<dim3(NN / 64, BB), dim3(64), 0, stream>>>(qpos, idxk);
  mlp_kernel<<<dim3(BB * NN * KK), dim3(64), 0, stream>>>(U, V, c1, lng, lnb, W2, idxk, qpos, shp);
  three_nn_kernel<<<dim3(NKK / 64, BB), dim3(64), 0, stream>>>(qpos, shp, w3, i3);
  final_kernel<<<dim3(NN, BB), dim3(CC), 0, stream>>>(P, Bse, w3, i3, out);
}

// Round 2
// 227.993 us; speedup vs baseline: 2.4231x; 2.4231x over previous
//
#include <hip/hip_runtime.h>
#include <math.h>

#define BB 4
#define NN 1024
#define CC 384
#define KK 10
#define NKK (NN*KK)
#define NC4 (4*CC)   // 1536, fused GEMM output width

__device__ __forceinline__ float wave_sum(float v) {
  #pragma unroll
  for (int off = 32; off > 0; off >>= 1) v += __shfl_xor(v, off, 64);
  return v;
}

// ---------------- bias_cat = [0 | c1 | 0 | bk], c1 = bv@W1_top + b1 ------------------
__global__ void biascat_kernel(const float* __restrict__ W1, const float* __restrict__ b1,
                               const float* __restrict__ bv, const float* __restrict__ bk,
                               float* __restrict__ bias_cat) {
  int j = blockIdx.x * 256 + threadIdx.x;
  if (j < NC4) {
    float v = 0.f;
    if (j >= CC && j < 2 * CC) {
      int c = j - CC;
      float s = b1[c];
      for (int i = 0; i < CC; ++i) s += bv[i] * W1[i * CC + c];
      v = s;
    } else if (j >= 3 * CC) {
      v = bk[j - 3 * CC];
    }
    bias_cat[j] = v;
  }
}

// ---------------- Bcat[r, :] = [M1[r,:] | W1_bot[r,:] | Wk_top[r,:] | Wk_bot-Wk_top] --
__global__ void pack_kernel(const float* __restrict__ M1, const float* __restrict__ W1,
                            const float* __restrict__ Wk, float* __restrict__ Bcat) {
  int idx = blockIdx.x * 256 + threadIdx.x;
  if (idx < CC * CC) {
    int r = idx / CC, j = idx % CC;
    float wkt = Wk[idx];
    float* br = Bcat + (size_t)r * NC4;
    br[j]          = M1[idx];
    br[CC + j]     = W1[(size_t)(CC + r) * CC + j];
    br[2 * CC + j] = wkt;
    br[3 * CC + j] = Wk[(size_t)CC * CC + idx] - wkt;
  }
}

// ---------------- generic f32 GEMM: C[M,Ncol] = A[M,Kd]@B[Kd,Ncol] (+bias) ----------
__global__ __launch_bounds__(256) void gemm_kernel(
    const float* __restrict__ A, const float* __restrict__ Bm,
    float* __restrict__ Cm, const float* __restrict__ bias,
    int M, int Ncol, int Kd) {
  __shared__ float As[16][64];
  __shared__ float Bs[16][64];
  int tid = threadIdx.x;
  int tx = tid & 15, ty = tid >> 4;
  int row0 = blockIdx.y * 64, col0 = blockIdx.x * 64;
  int arow = tid >> 2, ak4 = (tid & 3) << 2;
  int brow = tid >> 4, bc4 = (tid & 15) << 2;
  float acc[4][4] = {};
  for (int kt = 0; kt < Kd; kt += 16) {
    float4 av = *reinterpret_cast<const float4*>(A + (size_t)(row0 + arow) * Kd + kt + ak4);
    float4 bv4 = *reinterpret_cast<const float4*>(Bm + (size_t)(kt + brow) * Ncol + col0 + bc4);
    As[ak4 + 0][arow] = av.x;
    As[ak4 + 1][arow] = av.y;
    As[ak4 + 2][arow] = av.z;
    As[ak4 + 3][arow] = av.w;
    *reinterpret_cast<float4*>(&Bs[brow][bc4]) = bv4;
    __syncthreads();
    #pragma unroll
    for (int kk = 0; kk < 16; ++kk) {
      float4 a = *reinterpret_cast<const float4*>(&As[kk][ty << 2]);
      float4 bb = *reinterpret_cast<const float4*>(&Bs[kk][tx << 2]);
      float av_[4] = {a.x, a.y, a.z, a.w};
      float bv_[4] = {bb.x, bb.y, bb.z, bb.w};
      #pragma unroll
      for (int i = 0; i < 4; ++i)
        #pragma unroll
        for (int j = 0; j < 4; ++j)
          acc[i][j] += av_[i] * bv_[j];
    }
    __syncthreads();
  }
  #pragma unroll
  for (int i = 0; i < 4; ++i) {
    int row = row0 + (ty << 2) + i;
    int col = col0 + (tx << 2);
    float4 r;
    r.x = acc[i][0]; r.y = acc[i][1]; r.z = acc[i][2]; r.w = acc[i][3];
    if (bias) { r.x += bias[col]; r.y += bias[col + 1]; r.z += bias[col + 2]; r.w += bias[col + 3]; }
    *reinterpret_cast<float4*>(Cm + (size_t)row * Ncol + col) = r;
  }
}

// ---------------- KNN: one WAVE per query point; lanes split the 1024 candidates -----
__global__ __launch_bounds__(256) void knn_kernel(const float* __restrict__ q_pos,
                                                  int* __restrict__ idx_out) {
  __shared__ float sx[NN], sy[NN], sz[NN];
  int b = blockIdx.y;
  int t = threadIdx.x;
  const float* qp = q_pos + (size_t)b * NN * 3;
  for (int i = t; i < NN; i += 256) {
    sx[i] = qp[i * 3 + 0]; sy[i] = qp[i * 3 + 1]; sz[i] = qp[i * 3 + 2];
  }
  __syncthreads();
  int wave = t >> 6, lane = t & 63;
  int n = blockIdx.x * 4 + wave;
  double px = (double)sx[n], py = (double)sy[n], pz = (double)sz[n];
  double sp = px * px + py * py + pz * pz;
  // per-lane sorted top-10 over its 16 candidates (static indexing only)
  double bd[KK]; int bi[KK];
  #pragma unroll
  for (int s = 0; s < KK; ++s) { bd[s] = 1e300; bi[s] = -1; }
  #pragma unroll 4
  for (int j = 0; j < 16; ++j) {
    int m = lane + (j << 6);
    double mx = (double)sx[m], my = (double)sy[m], mz = (double)sz[m];
    double d = sp + (mx * mx + my * my + mz * mz) - 2.0 * (px * mx + py * my + pz * mz);
    if (d < 0.0) d = 0.0;
    if (d < bd[KK - 1]) {
      bd[KK - 1] = d; bi[KK - 1] = m;
      #pragma unroll
      for (int s = KK - 1; s >= 1; --s) {
        if (bd[s] < bd[s - 1]) {
          double td = bd[s]; bd[s] = bd[s - 1]; bd[s - 1] = td;
          int ti = bi[s]; bi[s] = bi[s - 1]; bi[s - 1] = ti;
        }
      }
    }
  }
  // 10 extraction rounds: wave-argmin of heads, tie -> smaller index (stable top_k)
  int* op = idx_out + ((size_t)b * NN + n) * KK;
  for (int s = 0; s < KK; ++s) {
    double d = bd[0]; int i = bi[0];
    #pragma unroll
    for (int off = 32; off > 0; off >>= 1) {
      double od = __shfl_xor(d, off, 64);
      int oi = __shfl_xor(i, off, 64);
      if (od < d || (od == d && oi < i)) { d = od; i = oi; }
    }
    if (bi[0] == i) {   // this lane owned the winner: pop (static unrolled shift)
      #pragma unroll
      for (int u = 0; u < KK - 1; ++u) { bd[u] = bd[u + 1]; bi[u] = bi[u + 1]; }
      bd[KK - 1] = 1e300; bi[KK - 1] = -1;
    }
    if (lane == 0) op[s] = i;
  }
}

// -------- fused MLP per (b,n): loop k; h=U[idx]+V -> LN -> gelu -> tanh(h@W2) --------
__global__ __launch_bounds__(64) void mlp_kernel(
    const float* __restrict__ Cat, const float* __restrict__ lng, const float* __restrict__ lnb,
    const float* __restrict__ W2, const int* __restrict__ idxk, const float* __restrict__ q_pos,
    float* __restrict__ shp) {
  int bn = blockIdx.x;            // b*NN+n
  int b = bn >> 10;
  int lane = threadIdx.x;
  __shared__ int s_nb[KK];
  __shared__ float s_scale[3], s_lvp[KK][3];
  if (lane < KK) s_nb[lane] = idxk[(size_t)bn * KK + lane];
  __syncthreads();
  if (lane < 3) {
    float mx = -1e30f, mn = 1e30f;
    #pragma unroll
    for (int k2 = 0; k2 < KK; ++k2) {
      float v = q_pos[((size_t)b * NN + s_nb[k2]) * 3 + lane];
      mx = fmaxf(mx, v); mn = fminf(mn, v);
      s_lvp[k2][lane] = v;
    }
    s_scale[lane] = (mx - mn) * 0.5f;
  }
  __syncthreads();
  float Vv[6], lg[6], lb[6], w2a[6], w2b[6], w2c[6];
  const float* Vrow = Cat + (size_t)bn * NC4 + CC;
  #pragma unroll
  for (int i = 0; i < 6; ++i) {
    int c = lane + (i << 6);
    Vv[i] = Vrow[c];
    lg[i] = lng[c]; lb[i] = lnb[c];
    w2a[i] = W2[c * 3 + 0]; w2b[i] = W2[c * 3 + 1]; w2c[i] = W2[c * 3 + 2];
  }
  for (int k = 0; k < KK; ++k) {
    const float* Urow = Cat + ((size_t)b * NN + s_nb[k]) * NC4;
    float h[6];
    float ls = 0.f;
    #pragma unroll
    for (int i = 0; i < 6; ++i) {
      h[i] = Urow[lane + (i << 6)] + Vv[i];
      ls += h[i];
    }
    ls = wave_sum(ls);
    float mu = ls * (1.0f / CC);
    float lv = 0.f;
    #pragma unroll
    for (int i = 0; i < 6; ++i) { float d = h[i] - mu; lv += d * d; }
    lv = wave_sum(lv);
    float rstd = 1.0f / sqrtf(lv * (1.0f / CC) + 1e-5f);
    float o0 = 0.f, o1 = 0.f, o2 = 0.f;
    #pragma unroll
    for (int i = 0; i < 6; ++i) {
      float x = (h[i] - mu) * rstd * lg[i] + lb[i];
      float g = 0.5f * x * (1.0f + erff(x * 0.70710678118654752440f));  // exact gelu
      o0 += g * w2a[i]; o1 += g * w2b[i]; o2 += g * w2c[i];
    }
    o0 = wave_sum(o0); o1 = wave_sum(o1); o2 = wave_sum(o2);
    if (lane == 0) {
      float* sp = shp + ((size_t)bn * KK + k) * 3;
      sp[0] = s_lvp[k][0] + tanhf(o0) * s_scale[0];
      sp[1] = s_lvp[k][1] + tanhf(o1) * s_scale[1];
      sp[2] = s_lvp[k][2] + tanhf(o2) * s_scale[2];
    }
  }
}

// ---------------- three_nn: one WAVE per shifted point; 3 extraction rounds ----------
__global__ __launch_bounds__(256) void three_nn_kernel(
    const float* __restrict__ q_pos, const float* __restrict__ shp,
    float* __restrict__ w3, int* __restrict__ i3) {
  __shared__ float sx[NN], sy[NN], sz[NN];
  int b = blockIdx.y;
  int t = threadIdx.x;
  const float* qp = q_pos + (size_t)b * NN * 3;
  for (int i = t; i < NN; i += 256) {
    sx[i] = qp[i * 3 + 0]; sy[i] = qp[i * 3 + 1]; sz[i] = qp[i * 3 + 2];
  }
  __syncthreads();
  int wave = t >> 6, lane = t & 63;
  int p = blockIdx.x * 4 + wave;
  const float* spnt = shp + ((size_t)b * NKK + p) * 3;
  double px = (double)spnt[0], py = (double)spnt[1], pz = (double)spnt[2];
  double sp = px * px + py * py + pz * pz;
  double d0 = 1e300, d1 = 1e300, d2 = 1e300;
  int i0 = -1, i1 = -1, i2 = -1;
  #pragma unroll 4
  for (int j = 0; j < 16; ++j) {
    int m = lane + (j << 6);
    double mx = (double)sx[m], my = (double)sy[m], mz = (double)sz[m];
    double d = sp + (mx * mx + my * my + mz * mz) - 2.0 * (px * mx + py * my + pz * mz);
    if (d < 0.0) d = 0.0;
    if (d < d2) {
      if (d < d1) {
        d2 = d1; i2 = i1;
        if (d < d0) { d1 = d0; i1 = i0; d0 = d; i0 = m; }
        else { d1 = d; i1 = m; }
      } else { d2 = d; i2 = m; }
    }
  }
  double wd[3]; int wi[3];
  #pragma unroll
  for (int s = 0; s < 3; ++s) {
    double d = d0; int i = i0;
    #pragma unroll
    for (int off = 32; off > 0; off >>= 1) {
      double od = __shfl_xor(d, off, 64);
      int oi = __shfl_xor(i, off, 64);
      if (od < d || (od == d && oi < i)) { d = od; i = oi; }
    }
    if (i0 == i) { d0 = d1; i0 = i1; d1 = d2; i1 = i2; d2 = 1e300; i2 = -1; }
    wd[s] = d; wi[s] = i;
  }
  if (lane == 0) {
    double w0 = 1.0 / (wd[0] + 1e-8), w1 = 1.0 / (wd[1] + 1e-8), w2 = 1.0 / (wd[2] + 1e-8);
    double s = w0 + w1 + w2;
    float* wp = w3 + ((size_t)b * NKK + p) * 3;
    int* ip = i3 + ((size_t)b * NKK + p) * 3;
    wp[0] = (float)(w0 / s); wp[1] = (float)(w1 / s); wp[2] = (float)(w2 / s);
    ip[0] = wi[0]; ip[1] = wi[1]; ip[2] = wi[2];
  }
}

// ------- final: out[b,n,j] = max_k lrelu( sum_t w*P[idx3_t,j] + Bse[b,n,j] ) ---------
__global__ __launch_bounds__(384) void final_kernel(
    const float* __restrict__ Cat,
    const float* __restrict__ w3, const int* __restrict__ i3,
    float* __restrict__ out) {
  int b = blockIdx.y, n = blockIdx.x;
  int j = threadIdx.x;
  __shared__ float sw[KK * 3];
  __shared__ int si[KK * 3];
  if (j < KK * 3) {
    size_t base = ((size_t)b * NKK + (size_t)n * KK) * 3 + j;
    sw[j] = w3[base];
    si[j] = i3[base];
  }
  __syncthreads();
  int bn = b * NN + n;
  float base = Cat[(size_t)bn * NC4 + 3 * CC + j];   // Bse
  const float* Pb = Cat + (size_t)b * NN * NC4 + 2 * CC;
  float best = -1e30f;
  #pragma unroll
  for (int k = 0; k < KK; ++k) {
    float acc = base;
    #pragma unroll
    for (int tt = 0; tt < 3; ++tt)
      acc += sw[k * 3 + tt] * Pb[(size_t)si[k * 3 + tt] * NC4 + j];
    acc = acc >= 0.f ? acc : 0.2f * acc;
    best = fmaxf(best, acc);
  }
  out[(size_t)bn * CC + j] = best;
}

extern "C" void kernel_launch(void* const* d_in, const int* in_sizes, int n_in,
                              void* d_out, int out_size, void* d_ws, size_t ws_size,
                              hipStream_t stream) {
  (void)in_sizes; (void)n_in; (void)out_size; (void)ws_size;
  const float* q    = (const float*)d_in[0];
  const float* qpos = (const float*)d_in[1];
  const float* Wv   = (const float*)d_in[2];
  const float* bv   = (const float*)d_in[3];
  const float* W1   = (const float*)d_in[4];
  const float* b1   = (const float*)d_in[5];
  const float* lng  = (const float*)d_in[6];
  const float* lnb  = (const float*)d_in[7];
  const float* W2   = (const float*)d_in[8];
  const float* Wk   = (const float*)d_in[9];
  const float* bk   = (const float*)d_in[10];
  float* out = (float*)d_out;

  float* ws = (float*)d_ws;
  float* Cat = ws;                 // [4096, 1536] = U|V|P|Bse
  float* M1  = Cat;                // aliased: M1 dead before Cat is written
  ws += (size_t)BB * NN * NC4;
  float* Bcat = ws; ws += (size_t)CC * NC4;
  float* bias_cat = ws; ws += NC4;
  float* shp = ws; ws += (size_t)BB * NKK * 3;
  float* w3  = ws; ws += (size_t)BB * NKK * 3;
  int* idxk = (int*)ws;
  int* i3   = idxk + (size_t)BB * NN * KK;

  // M1 = Wv @ W1_top
  gemm_kernel<<<dim3(CC / 64, CC / 64), dim3(256), 0, stream>>>(Wv, W1, M1, nullptr, CC, CC, CC);
  biascat_kernel<<<dim3((NC4 + 255) / 256), dim3(256), 0, stream>>>(W1, b1, bv, bk, bias_cat);
  pack_kernel<<<dim3((CC * CC + 255) / 256), dim3(256), 0, stream>>>(M1, W1, Wk, Bcat);
  // Cat = q @ Bcat + bias_cat   (U | V+c1 | P | Bse+bk)
  gemm_kernel<<<dim3(NC4 / 64, BB * NN / 64), dim3(256), 0, stream>>>(q, Bcat, Cat, bias_cat, BB * NN, NC4, CC);

  knn_kernel<<<dim3(NN / 4, BB), dim3(256), 0, stream>>>(qpos, idxk);
  mlp_kernel<<<dim3(BB * NN), dim3(64), 0, stream>>>(Cat, lng, lnb, W2, idxk, qpos, shp);
  three_nn_kernel<<<dim3(NKK / 4, BB), dim3(256), 0, stream>>>(qpos, shp, w3, i3);
  final_kernel<<<dim3(NN, BB), dim3(CC), 0, stream>>>(Cat, w3, i3, out);
}